// Round 1
// baseline (251.058 us; speedup 1.0000x reference)
//
#include <hip/hip_runtime.h>

// SetNorm: B=64, N=2048, D=256 fp32.
// out[b,n,d] = n < len[b] ? ((x[b,n,d] - mean_b) / (sqrt(var_b) + eps)) * w[d] + bias[d] : 0
// mean/var over the masked region (first len[b] rows, all D features), denom = len[b]*D.

#define BB 64
#define NN 2048
#define DD 256
#define EPSV 1e-5f
#define CHUNKS 8
#define ROWS_PER_CHUNK (NN / CHUNKS) // 256

// ---------- Kernel 1: per-(batch,chunk) partial sum / sumsq ----------
__global__ __launch_bounds__(256) void setnorm_partials(
    const float* __restrict__ x, const int* __restrict__ lengths,
    float* __restrict__ partials) {
  const int c = blockIdx.x;        // chunk within batch
  const int b = blockIdx.y;        // batch
  const int len = lengths[b];
  const int rowBase = c * ROWS_PER_CHUNK;
  int validRows = len - rowBase;
  if (validRows > ROWS_PER_CHUNK) validRows = ROWS_PER_CHUNK;

  float sum = 0.f, sumsq = 0.f;
  if (validRows > 0) {
    const float4* p =
        (const float4*)(x + ((size_t)b * NN + (size_t)rowBase) * DD);
    const int n4 = validRows * (DD / 4); // D divisible by 4; rows are whole
    for (int i = threadIdx.x; i < n4; i += blockDim.x) {
      float4 v = p[i];
      sum += v.x + v.y + v.z + v.w;
      sumsq += v.x * v.x + v.y * v.y + v.z * v.z + v.w * v.w;
    }
  }
  // wave64 butterfly reduce
  #pragma unroll
  for (int off = 32; off > 0; off >>= 1) {
    sum += __shfl_down(sum, off, 64);
    sumsq += __shfl_down(sumsq, off, 64);
  }
  __shared__ float ssum[4], ssq[4];
  const int wave = threadIdx.x >> 6;
  const int lane = threadIdx.x & 63;
  if (lane == 0) { ssum[wave] = sum; ssq[wave] = sumsq; }
  __syncthreads();
  if (threadIdx.x == 0) {
    float ts = 0.f, tq = 0.f;
    #pragma unroll
    for (int w = 0; w < 4; ++w) { ts += ssum[w]; tq += ssq[w]; }
    partials[(b * CHUNKS + c) * 2 + 0] = ts;
    partials[(b * CHUNKS + c) * 2 + 1] = tq;
  }
}

// ---------- Kernel 2: finalize per-batch stats ----------
__global__ __launch_bounds__(64) void setnorm_finalize(
    const float* __restrict__ partials, const int* __restrict__ lengths,
    float* __restrict__ stats) {
  const int b = threadIdx.x;
  if (b < BB) {
    float s = 0.f, q = 0.f;
    #pragma unroll
    for (int c = 0; c < CHUNKS; ++c) {
      s += partials[(b * CHUNKS + c) * 2 + 0];
      q += partials[(b * CHUNKS + c) * 2 + 1];
    }
    const float denom = (float)lengths[b] * (float)DD;
    const float mean = s / denom;
    float var = q / denom - mean * mean;
    var = fmaxf(var, 0.f);
    const float inv = 1.f / (sqrtf(var) + EPSV);
    stats[b * 2 + 0] = mean;
    stats[b * 2 + 1] = inv;
  }
}

// ---------- Kernel 3: normalize + affine + mask ----------
__global__ __launch_bounds__(256) void setnorm_normalize(
    const float* __restrict__ x, const int* __restrict__ lengths,
    const float* __restrict__ weights, const float* __restrict__ biases,
    const float* __restrict__ stats, float* __restrict__ out) {
  const int idx4 = blockIdx.x * blockDim.x + threadIdx.x; // < B*N*D/4 = 8388608
  const int b = idx4 >> 17;         // N*D/4 = 131072 = 2^17
  const int rem = idx4 & 131071;
  const int row = rem >> 6;         // D/4 = 64
  const int d4 = rem & 63;
  const int len = lengths[b];
  float4 o;
  if (row < len) {
    const float mean = stats[b * 2 + 0];
    const float inv = stats[b * 2 + 1];
    const float4 v = ((const float4*)x)[idx4];
    const float4 w = ((const float4*)weights)[d4];
    const float4 bi = ((const float4*)biases)[d4];
    o.x = (v.x - mean) * inv * w.x + bi.x;
    o.y = (v.y - mean) * inv * w.y + bi.y;
    o.z = (v.z - mean) * inv * w.z + bi.z;
    o.w = (v.w - mean) * inv * w.w + bi.w;
  } else {
    o.x = 0.f; o.y = 0.f; o.z = 0.f; o.w = 0.f;
  }
  ((float4*)out)[idx4] = o;
}

extern "C" void kernel_launch(void* const* d_in, const int* in_sizes, int n_in,
                              void* d_out, int out_size, void* d_ws, size_t ws_size,
                              hipStream_t stream) {
  const float* x = (const float*)d_in[0];
  const int* lengths = (const int*)d_in[1];
  const float* weights = (const float*)d_in[2];
  const float* biases = (const float*)d_in[3];
  float* out = (float*)d_out;

  float* partials = (float*)d_ws;                 // B*CHUNKS*2 floats
  float* stats = partials + BB * CHUNKS * 2;      // B*2 floats

  dim3 g1(CHUNKS, BB);
  setnorm_partials<<<g1, 256, 0, stream>>>(x, lengths, partials);
  setnorm_finalize<<<1, 64, 0, stream>>>(partials, lengths, stats);
  const int total4 = BB * NN * DD / 4; // 8388608
  setnorm_normalize<<<total4 / 256, 256, 0, stream>>>(x, lengths, weights,
                                                      biases, stats, out);
}

// Round 3
// 231.481 us; speedup vs baseline: 1.0846x; 1.0846x over previous
//
#include <hip/hip_runtime.h>

// SetNorm: B=64, N=2048, D=256 fp32.
// out[b,n,d] = n < len[b] ? ((x[b,n,d] - mean_b) / (sqrt(var_b) + eps)) * w[d] + bias[d] : 0
// mean/var over masked region (first len[b] rows), denom = len[b]*D.
//
// R3 = R2 with native vector type for nontemporal store (HIP float4 is a
// class; __builtin_nontemporal_store needs a native vector).

#define BB 64
#define NN 2048
#define DD 256
#define EPSV 1e-5f
#define CHUNKS 32
#define ROWS_PER_CHUNK (NN / CHUNKS) // 64

typedef float f32x4 __attribute__((ext_vector_type(4)));

// ---------- Kernel 1: per-(batch,chunk) partial sum / sumsq ----------
__global__ __launch_bounds__(256) void setnorm_partials(
    const float* __restrict__ x, const int* __restrict__ lengths,
    float* __restrict__ partials) {
  const int c = blockIdx.x;        // chunk within batch
  const int b = blockIdx.y;        // batch
  const int len = lengths[b];
  const int rowBase = c * ROWS_PER_CHUNK;
  int validRows = len - rowBase;
  if (validRows > ROWS_PER_CHUNK) validRows = ROWS_PER_CHUNK;

  float sum = 0.f, sumsq = 0.f;
  if (validRows > 0) {
    const f32x4* p =
        (const f32x4*)(x + ((size_t)b * NN + (size_t)rowBase) * DD);
    const int n4 = validRows * (DD / 4); // <= 4096, 16 iters/thread
    for (int i = threadIdx.x; i < n4; i += 256) {
      f32x4 v = p[i];
      sum += v.x + v.y + v.z + v.w;
      sumsq += v.x * v.x + v.y * v.y + v.z * v.z + v.w * v.w;
    }
  }
  // wave64 reduce
  #pragma unroll
  for (int off = 32; off > 0; off >>= 1) {
    sum += __shfl_down(sum, off, 64);
    sumsq += __shfl_down(sumsq, off, 64);
  }
  __shared__ float ssum[4], ssq[4];
  const int wave = threadIdx.x >> 6;
  const int lane = threadIdx.x & 63;
  if (lane == 0) { ssum[wave] = sum; ssq[wave] = sumsq; }
  __syncthreads();
  if (threadIdx.x == 0) {
    float ts = 0.f, tq = 0.f;
    #pragma unroll
    for (int w = 0; w < 4; ++w) { ts += ssum[w]; tq += ssq[w]; }
    partials[(b * CHUNKS + c) * 2 + 0] = ts;
    partials[(b * CHUNKS + c) * 2 + 1] = tq;
  }
}

// ---------- Kernel 2: finalize stats (per block, from L2) + normalize ----------
__global__ __launch_bounds__(256) void setnorm_norm(
    const float* __restrict__ x, const int* __restrict__ lengths,
    const float* __restrict__ weights, const float* __restrict__ biases,
    const float* __restrict__ partials, float* __restrict__ out) {
  const int idx4 = blockIdx.x * 256 + threadIdx.x; // < B*N*D/4
  const int b = idx4 >> 17;         // N*D/4 = 131072 = 2^17 (uniform per block)
  const int rem = idx4 & 131071;
  const int row = rem >> 6;         // D/4 = 64
  const int d4 = rem & 63;

  // wave 0 re-reduces this batch's 32 partial pairs (64 B, L2-hot)
  __shared__ float s_mean, s_inv;
  if (threadIdx.x < 64) {
    float s = 0.f, q = 0.f;
    if (threadIdx.x < CHUNKS) {
      s = partials[(b * CHUNKS + threadIdx.x) * 2 + 0];
      q = partials[(b * CHUNKS + threadIdx.x) * 2 + 1];
    }
    #pragma unroll
    for (int off = 16; off > 0; off >>= 1) {
      s += __shfl_down(s, off, 64);
      q += __shfl_down(q, off, 64);
    }
    if (threadIdx.x == 0) {
      const float denom = (float)lengths[b] * (float)DD;
      const float mean = s / denom;
      float var = q / denom - mean * mean;
      var = fmaxf(var, 0.f);
      s_mean = mean;
      s_inv = 1.f / (sqrtf(var) + EPSV);
    }
  }
  __syncthreads();

  const int len = lengths[b];
  f32x4 o = {0.f, 0.f, 0.f, 0.f};
  if (row < len) {
    const float mean = s_mean;
    const float inv = s_inv;
    const f32x4 v = ((const f32x4*)x)[idx4];
    const f32x4 w = ((const f32x4*)weights)[d4];
    const f32x4 bi = ((const f32x4*)biases)[d4];
    o.x = (v.x - mean) * inv * w.x + bi.x;
    o.y = (v.y - mean) * inv * w.y + bi.y;
    o.z = (v.z - mean) * inv * w.z + bi.z;
    o.w = (v.w - mean) * inv * w.w + bi.w;
  }
  // nontemporal: out is never re-read; don't evict x from L3
  __builtin_nontemporal_store(o, ((f32x4*)out) + idx4);
}

extern "C" void kernel_launch(void* const* d_in, const int* in_sizes, int n_in,
                              void* d_out, int out_size, void* d_ws, size_t ws_size,
                              hipStream_t stream) {
  const float* x = (const float*)d_in[0];
  const int* lengths = (const int*)d_in[1];
  const float* weights = (const float*)d_in[2];
  const float* biases = (const float*)d_in[3];
  float* out = (float*)d_out;

  float* partials = (float*)d_ws; // B*CHUNKS*2 floats = 4 KB

  dim3 g1(CHUNKS, BB); // 2048 blocks
  setnorm_partials<<<g1, 256, 0, stream>>>(x, lengths, partials);
  const int total4 = BB * NN * DD / 4; // 8388608
  setnorm_norm<<<total4 / 256, 256, 0, stream>>>(x, lengths, weights, biases,
                                                 partials, out);
}

// Round 4
// 230.085 us; speedup vs baseline: 1.0912x; 1.0061x over previous
//
#include <hip/hip_runtime.h>

// SetNorm: B=64, N=2048, D=256 fp32.
// out[b,n,d] = n < len[b] ? ((x[b,n,d] - mean_b) / (sqrt(var_b) + eps)) * w[d] + bias[d] : 0
//
// R4: normalize does 4x f32x4/thread (8192 blocks): amortizes per-block stats
// re-reduce, 4 loads in flight. Fully-invalid blocks zero-fill + exit without
// stats/barrier. partials 2-wide unrolled. w/bias loads hoisted.

#define BB 64
#define NN 2048
#define DD 256
#define EPSV 1e-5f
#define CHUNKS 32
#define ROWS_PER_CHUNK (NN / CHUNKS) // 64

typedef float f32x4 __attribute__((ext_vector_type(4)));

// ---------- Kernel 1: per-(batch,chunk) partial sum / sumsq ----------
__global__ __launch_bounds__(256) void setnorm_partials(
    const float* __restrict__ x, const int* __restrict__ lengths,
    float* __restrict__ partials) {
  const int c = blockIdx.x;
  const int b = blockIdx.y;
  const int len = lengths[b];
  const int rowBase = c * ROWS_PER_CHUNK;
  int validRows = len - rowBase;
  if (validRows > ROWS_PER_CHUNK) validRows = ROWS_PER_CHUNK;

  float sum = 0.f, sumsq = 0.f;
  if (validRows > 0) {
    const f32x4* p =
        (const f32x4*)(x + ((size_t)b * NN + (size_t)rowBase) * DD);
    const int n4 = validRows * (DD / 4); // <= 4096
    // 2-wide: two independent loads in flight per lane
    for (int i = threadIdx.x; i < n4; i += 512) {
      f32x4 v = p[i];
      sum += v.x + v.y + v.z + v.w;
      sumsq += v.x * v.x + v.y * v.y + v.z * v.z + v.w * v.w;
      const int j = i + 256;
      if (j < n4) {
        f32x4 u = p[j];
        sum += u.x + u.y + u.z + u.w;
        sumsq += u.x * u.x + u.y * u.y + u.z * u.z + u.w * u.w;
      }
    }
  }
  #pragma unroll
  for (int off = 32; off > 0; off >>= 1) {
    sum += __shfl_down(sum, off, 64);
    sumsq += __shfl_down(sumsq, off, 64);
  }
  __shared__ float ssum[4], ssq[4];
  const int wave = threadIdx.x >> 6;
  const int lane = threadIdx.x & 63;
  if (lane == 0) { ssum[wave] = sum; ssq[wave] = sumsq; }
  __syncthreads();
  if (threadIdx.x == 0) {
    float ts = 0.f, tq = 0.f;
    #pragma unroll
    for (int w = 0; w < 4; ++w) { ts += ssum[w]; tq += ssq[w]; }
    partials[(b * CHUNKS + c) * 2 + 0] = ts;
    partials[(b * CHUNKS + c) * 2 + 1] = tq;
  }
}

// ---------- Kernel 2: finalize stats + normalize, 4x f32x4/thread ----------
__global__ __launch_bounds__(256) void setnorm_norm(
    const float* __restrict__ x, const int* __restrict__ lengths,
    const float* __restrict__ weights, const float* __restrict__ biases,
    const float* __restrict__ partials, float* __restrict__ out) {
  const int blockBase = blockIdx.x * 1024;   // f32x4 units; block spans 16 rows
  const int b = blockBase >> 17;             // 131072 f32x4 per batch
  const int row0 = (blockBase & 131071) >> 6;
  const int len = lengths[b];

  // fully-invalid block: zero-fill 16 KB, no stats / no barrier
  if (row0 >= len) {
    const f32x4 z = {0.f, 0.f, 0.f, 0.f};
    #pragma unroll
    for (int i = 0; i < 4; ++i)
      __builtin_nontemporal_store(z,
          ((f32x4*)out) + blockBase + i * 256 + threadIdx.x);
    return;
  }

  // wave 0 re-reduces this batch's 32 partial pairs (64 B, L2-hot)
  __shared__ float s_mean, s_inv;
  if (threadIdx.x < 64) {
    float s = 0.f, q = 0.f;
    if (threadIdx.x < CHUNKS) {
      s = partials[(b * CHUNKS + threadIdx.x) * 2 + 0];
      q = partials[(b * CHUNKS + threadIdx.x) * 2 + 1];
    }
    #pragma unroll
    for (int off = 16; off > 0; off >>= 1) {
      s += __shfl_down(s, off, 64);
      q += __shfl_down(q, off, 64);
    }
    if (threadIdx.x == 0) {
      const float denom = (float)lengths[b] * (float)DD;
      const float mean = s / denom;
      float var = q / denom - mean * mean;
      var = fmaxf(var, 0.f);
      s_mean = mean;
      s_inv = 1.f / (sqrtf(var) + EPSV);
    }
  }
  __syncthreads();
  const float mean = s_mean;
  const float inv = s_inv;

  const int d4 = threadIdx.x & 63;           // iteration-invariant
  const f32x4 w = ((const f32x4*)weights)[d4];
  const f32x4 bi = ((const f32x4*)biases)[d4];
  const int rowT = row0 + (threadIdx.x >> 6); // this thread's row in iter 0

  #pragma unroll
  for (int i = 0; i < 4; ++i) {
    const int idx4 = blockBase + i * 256 + threadIdx.x;
    const int row = rowT + i * 4;            // 256 f32x4 = 4 rows per iter
    f32x4 o = {0.f, 0.f, 0.f, 0.f};
    if (row < len) {
      const f32x4 v = ((const f32x4*)x)[idx4];
      o.x = (v.x - mean) * inv * w.x + bi.x;
      o.y = (v.y - mean) * inv * w.y + bi.y;
      o.z = (v.z - mean) * inv * w.z + bi.z;
      o.w = (v.w - mean) * inv * w.w + bi.w;
    }
    __builtin_nontemporal_store(o, ((f32x4*)out) + idx4);
  }
}

extern "C" void kernel_launch(void* const* d_in, const int* in_sizes, int n_in,
                              void* d_out, int out_size, void* d_ws, size_t ws_size,
                              hipStream_t stream) {
  const float* x = (const float*)d_in[0];
  const int* lengths = (const int*)d_in[1];
  const float* weights = (const float*)d_in[2];
  const float* biases = (const float*)d_in[3];
  float* out = (float*)d_out;

  float* partials = (float*)d_ws; // B*CHUNKS*2 floats = 16 KB

  dim3 g1(CHUNKS, BB); // 2048 blocks
  setnorm_partials<<<g1, 256, 0, stream>>>(x, lengths, partials);
  const int total4 = BB * NN * DD / 4;      // 8388608 f32x4
  setnorm_norm<<<total4 / 1024, 256, 0, stream>>>(x, lengths, weights, biases,
                                                  partials, out);
}